// Round 1
// baseline (434.069 us; speedup 1.0000x reference)
//
#include <hip/hip_runtime.h>

#define NCLS 19
#define NSAMP 4
#define HWSZ (512*1024)
#define NPIX (NSAMP*HWSZ)

// ws 4-byte-word offsets
#define OFF_NL_SEG   0      // float [4][19]  sum of -logp per (n,class)
#define OFF_CNT_SEG  76     // uint  [4][19]  pixel count per (n,class)
#define OFF_NL_ATT   152    // float [4][19]  same, edge-kept pixels only
#define OFF_CNT_ATT  228    // uint  [4][19]
#define OFF_BCE_POS  304    // float  sum of bce over mask==1
#define OFF_BCE_NEG  305    // float  sum of bce over mask==0
#define OFF_CNT_POS  306    // uint
#define OFF_CNT_NEG  307    // uint
#define WS_WORDS     308

__global__ void init_ws(unsigned int* ws) {
    int i = threadIdx.x;
    if (i < WS_WORDS) ws[i] = 0u;
}

__global__ __launch_bounds__(256) void joint_loss_main(
    const float* __restrict__ seg, const float* __restrict__ edge,
    const int* __restrict__ smask, const int* __restrict__ emask,
    float* __restrict__ wsf)
{
    unsigned int* wsu = (unsigned int*)wsf;
    __shared__ float        s_nl_seg[NCLS], s_nl_att[NCLS];
    __shared__ unsigned int s_cnt_seg[NCLS], s_cnt_att[NCLS];
    __shared__ float        s_bce[2];
    __shared__ unsigned int s_ecnt[2];

    const int tid = threadIdx.x;
    if (tid < NCLS) { s_nl_seg[tid]=0.f; s_nl_att[tid]=0.f; s_cnt_seg[tid]=0u; s_cnt_att[tid]=0u; }
    if (tid < 2)    { s_bce[tid]=0.f; s_ecnt[tid]=0u; }
    __syncthreads();

    const int i  = blockIdx.x * 256 + tid;        // pixel index, exact cover
    const int n  = blockIdx.x / (HWSZ / 256);     // block-uniform sample idx
    const int hw = i - n * HWSZ;
    const int t  = smask[i];
    const float ev = edge[i];
    const int te = emask[i];

    // ---- log-softmax over 19 channels, all in registers (static indexing) ----
    const float* p = seg + (size_t)n * NCLS * HWSZ + hw;
    float v[NCLS];
#pragma unroll
    for (int c = 0; c < NCLS; ++c) v[c] = p[(size_t)c * HWSZ];
    float m = v[0];
#pragma unroll
    for (int c = 1; c < NCLS; ++c) m = fmaxf(m, v[c]);
    float s = 0.f, xt = v[0];
#pragma unroll
    for (int c = 0; c < NCLS; ++c) {
        s += __expf(v[c] - m);
        if (c == t) xt = v[c];                    // select, stays in regs
    }
    const float neglogp = -(xt - m - __logf(s));

    // ---- per-(n,class) accumulation via LDS atomics ----
    if (t >= 0 && t < NCLS) {                     // 255-ignore handled generically
        atomicAdd(&s_nl_seg[t], neglogp);
        atomicAdd(&s_cnt_seg[t], 1u);
        if (ev > 0.8f) {                          // attention keep
            atomicAdd(&s_nl_att[t], neglogp);
            atomicAdd(&s_cnt_att[t], 1u);
        }
    }

    // ---- stable BCE-with-logits partial sums ----
    const float bce = fmaxf(ev, 0.f) - ev * (float)te + log1pf(__expf(-fabsf(ev)));
    if (te == 1)      { atomicAdd(&s_bce[0], bce); atomicAdd(&s_ecnt[0], 1u); }
    else if (te == 0) { atomicAdd(&s_bce[1], bce); atomicAdd(&s_ecnt[1], 1u); }

    __syncthreads();
    // ---- flush block partials to global ----
    if (tid < NCLS) {
        if (s_cnt_seg[tid]) {
            atomicAdd(&wsf[OFF_NL_SEG  + n*NCLS + tid], s_nl_seg[tid]);
            atomicAdd(&wsu[OFF_CNT_SEG + n*NCLS + tid], s_cnt_seg[tid]);
        }
        if (s_cnt_att[tid]) {
            atomicAdd(&wsf[OFF_NL_ATT  + n*NCLS + tid], s_nl_att[tid]);
            atomicAdd(&wsu[OFF_CNT_ATT + n*NCLS + tid], s_cnt_att[tid]);
        }
    }
    if (tid == 0 && s_ecnt[0]) { atomicAdd(&wsf[OFF_BCE_POS], s_bce[0]); atomicAdd(&wsu[OFF_CNT_POS], s_ecnt[0]); }
    if (tid == 1 && s_ecnt[1]) { atomicAdd(&wsf[OFF_BCE_NEG], s_bce[1]); atomicAdd(&wsu[OFF_CNT_NEG], s_ecnt[1]); }
}

__global__ void finalize(const float* __restrict__ wsf, float* __restrict__ out) {
    if (threadIdx.x != 0 || blockIdx.x != 0) return;
    const unsigned int* wsu = (const unsigned int*)wsf;

    float hist[NCLS], w[NCLS];

    // seg branch: weights from full-batch histogram, then per-sample mean NLL
    float tot = 0.f;
    for (int c = 0; c < NCLS; ++c) {
        float h = 0.f;
        for (int n = 0; n < NSAMP; ++n) h += (float)wsu[OFF_CNT_SEG + n*NCLS + c];
        hist[c] = h; tot += h;
    }
    for (int c = 0; c < NCLS; ++c)
        w[c] = 1.f + ((hist[c] != 0.f) ? (1.f - hist[c] / tot) : 0.f);
    float seg_loss = 0.f;
    for (int n = 0; n < NSAMP; ++n) {
        float num = 0.f, den = 0.f;
        for (int c = 0; c < NCLS; ++c) {
            num += w[c] * wsf[OFF_NL_SEG + n*NCLS + c];
            den += w[c] * (float)wsu[OFF_CNT_SEG + n*NCLS + c];
        }
        seg_loss += num / den;
    }

    // att branch
    tot = 0.f;
    for (int c = 0; c < NCLS; ++c) {
        float h = 0.f;
        for (int n = 0; n < NSAMP; ++n) h += (float)wsu[OFF_CNT_ATT + n*NCLS + c];
        hist[c] = h; tot += h;
    }
    for (int c = 0; c < NCLS; ++c)
        w[c] = 1.f + ((hist[c] != 0.f) ? (1.f - hist[c] / tot) : 0.f);
    float att_loss = 0.f;
    for (int n = 0; n < NSAMP; ++n) {
        float num = 0.f, den = 0.f;
        for (int c = 0; c < NCLS; ++c) {
            num += w[c] * wsf[OFF_NL_ATT + n*NCLS + c];
            den += w[c] * (float)wsu[OFF_CNT_ATT + n*NCLS + c];
        }
        att_loss += num / den;
    }

    // edge branch: mean(w * bce) over ALL elements, w from pos/neg counts
    float pos = (float)wsu[OFF_CNT_POS], neg = (float)wsu[OFF_CNT_NEG];
    float tt = pos + neg;
    float bce_mean = ((neg / tt) * wsf[OFF_BCE_POS] + (pos / tt) * wsf[OFF_BCE_NEG])
                     / (float)NPIX;

    out[0] = seg_loss;
    out[1] = 20.f * bce_mean;
    out[2] = att_loss;
}

extern "C" void kernel_launch(void* const* d_in, const int* in_sizes, int n_in,
                              void* d_out, int out_size, void* d_ws, size_t ws_size,
                              hipStream_t stream) {
    const float* segin   = (const float*)d_in[0];
    const float* edgein  = (const float*)d_in[1];
    const int*   segmask = (const int*)d_in[2];
    const int*   edgemask= (const int*)d_in[3];
    float* wsf = (float*)d_ws;
    float* out = (float*)d_out;

    init_ws<<<1, 512, 0, stream>>>((unsigned int*)d_ws);
    joint_loss_main<<<NPIX / 256, 256, 0, stream>>>(segin, edgein, segmask, edgemask, wsf);
    finalize<<<1, 64, 0, stream>>>(wsf, out);
}

// Round 2
// 48.515 us; speedup vs baseline: 8.9471x; 8.9471x over previous
//
#include <hip/hip_runtime.h>

#define NCLS 19
#define NSAMP 4
#define HWSZ (512*1024)
#define NPIX (NSAMP*HWSZ)

#define NBLK 1024                        // main-kernel blocks
#define BLK_PER_SAMP (NBLK/NSAMP)        // 256
#define PIX_PER_BLK (HWSZ/BLK_PER_SAMP)  // 2048 pixels per block
#define NSLOT 80
// slot layout: [0,19) nl_seg | [19,38) cnt_seg | [38,57) nl_att | [57,76) cnt_att
//              76 bce_pos | 77 bce_neg | 78 cnt_pos | 79 cnt_neg
#define FINAL_OFF (NSLOT*NBLK)           // word offset of the 4x80 reduced sums

__global__ __launch_bounds__(256, 4) void joint_loss_main(
    const float* __restrict__ seg, const float* __restrict__ edge,
    const int* __restrict__ smask, const int* __restrict__ emask,
    float* __restrict__ ws)
{
    __shared__ float sacc[NSLOT];
    const int tid = threadIdx.x;
    if (tid < NSLOT) sacc[tid] = 0.f;
    __syncthreads();

    const int n     = blockIdx.x / BLK_PER_SAMP;   // block-uniform sample
    const int chunk = blockIdx.x % BLK_PER_SAMP;
    const float* segn = seg + (size_t)n * NCLS * HWSZ;

    float bp = 0.f, bn = 0.f, cp = 0.f, cn = 0.f;  // bce partials in registers

#pragma unroll
    for (int rep = 0; rep < 2; ++rep) {
        const int pix = chunk * PIX_PER_BLK + rep * 1024 + tid * 4; // in-sample
        const size_t g = (size_t)n * HWSZ + pix;

        const float4 e4  = *reinterpret_cast<const float4*>(edge  + g);
        const int4   t4  = *reinterpret_cast<const int4*>(smask + g);
        const int4   te4 = *reinterpret_cast<const int4*>(emask + g);

        float4 v[NCLS];
#pragma unroll
        for (int c = 0; c < NCLS; ++c)
            v[c] = *reinterpret_cast<const float4*>(segn + (size_t)c * HWSZ + pix);

#pragma unroll
        for (int j = 0; j < 4; ++j) {
            const int   tj  = (j==0)?t4.x :(j==1)?t4.y :(j==2)?t4.z :t4.w;
            const int   tej = (j==0)?te4.x:(j==1)?te4.y:(j==2)?te4.z:te4.w;
            const float ej  = (j==0)?e4.x :(j==1)?e4.y :(j==2)?e4.z :e4.w;

            float x[NCLS];
#pragma unroll
            for (int c = 0; c < NCLS; ++c)
                x[c] = (j==0)?v[c].x:(j==1)?v[c].y:(j==2)?v[c].z:v[c].w;

            float m = x[0];
#pragma unroll
            for (int c = 1; c < NCLS; ++c) m = fmaxf(m, x[c]);
            float s = 0.f, xt = x[0];
#pragma unroll
            for (int c = 0; c < NCLS; ++c) {
                s += __expf(x[c] - m);
                if (c == tj) xt = x[c];            // static-index select
            }
            const float nl = -(xt - m - __logf(s));

            if (tj >= 0 && tj < NCLS) {            // ignore-255 guard
                atomicAdd(&sacc[tj], nl);
                atomicAdd(&sacc[NCLS + tj], 1.f);
                if (ej > 0.8f) {                   // attention keep
                    atomicAdd(&sacc[2*NCLS + tj], nl);
                    atomicAdd(&sacc[3*NCLS + tj], 1.f);
                }
            }

            const float b = fmaxf(ej, 0.f) - ej * (float)tej
                            + log1pf(__expf(-fabsf(ej)));
            if (tej == 1)      { bp += b; cp += 1.f; }
            else if (tej == 0) { bn += b; cn += 1.f; }
        }
    }

    // wave-level reduce of the register BCE partials, one LDS atomic per wave
#pragma unroll
    for (int off = 32; off; off >>= 1) {
        bp += __shfl_down(bp, off); bn += __shfl_down(bn, off);
        cp += __shfl_down(cp, off); cn += __shfl_down(cn, off);
    }
    if ((tid & 63) == 0) {
        atomicAdd(&sacc[76], bp); atomicAdd(&sacc[77], bn);
        atomicAdd(&sacc[78], cp); atomicAdd(&sacc[79], cn);
    }
    __syncthreads();

    // plain stores: partial[slot][block] — no global atomics anywhere
    if (tid < NSLOT) ws[(size_t)tid * NBLK + blockIdx.x] = sacc[tid];
}

// 320 blocks x 64 threads: block r reduces (n = r/80, slot = r%80)
__global__ void reduce_partials(const float* __restrict__ ws,
                                float* __restrict__ fin)
{
    const int r = blockIdx.x;
    const int n = r / NSLOT, slot = r % NSLOT;
    const int lane = threadIdx.x;
    const float* p = ws + (size_t)slot * NBLK + n * BLK_PER_SAMP;
    float s = p[lane] + p[lane + 64] + p[lane + 128] + p[lane + 192];
#pragma unroll
    for (int off = 32; off; off >>= 1) s += __shfl_down(s, off);
    if (lane == 0) fin[n * NSLOT + slot] = s;
}

__global__ void finalize(const float* __restrict__ fin, float* __restrict__ out)
{
    if (threadIdx.x != 0 || blockIdx.x != 0) return;

    float hist[NCLS], w[NCLS];

    // seg branch: weights from full-batch histogram
    float tot = 0.f;
    for (int c = 0; c < NCLS; ++c) {
        float h = 0.f;
        for (int n = 0; n < NSAMP; ++n) h += fin[n*NSLOT + NCLS + c];
        hist[c] = h; tot += h;
    }
    for (int c = 0; c < NCLS; ++c)
        w[c] = 1.f + ((hist[c] != 0.f) ? (1.f - hist[c] / tot) : 0.f);
    float seg_loss = 0.f;
    for (int n = 0; n < NSAMP; ++n) {
        float num = 0.f, den = 0.f;
        for (int c = 0; c < NCLS; ++c) {
            num += w[c] * fin[n*NSLOT + c];
            den += w[c] * fin[n*NSLOT + NCLS + c];
        }
        seg_loss += num / den;
    }

    // att branch
    tot = 0.f;
    for (int c = 0; c < NCLS; ++c) {
        float h = 0.f;
        for (int n = 0; n < NSAMP; ++n) h += fin[n*NSLOT + 3*NCLS + c];
        hist[c] = h; tot += h;
    }
    for (int c = 0; c < NCLS; ++c)
        w[c] = 1.f + ((hist[c] != 0.f) ? (1.f - hist[c] / tot) : 0.f);
    float att_loss = 0.f;
    for (int n = 0; n < NSAMP; ++n) {
        float num = 0.f, den = 0.f;
        for (int c = 0; c < NCLS; ++c) {
            num += w[c] * fin[n*NSLOT + 2*NCLS + c];
            den += w[c] * fin[n*NSLOT + 3*NCLS + c];
        }
        att_loss += num / den;
    }

    // edge branch
    float pos = 0.f, neg = 0.f, bpos = 0.f, bneg = 0.f;
    for (int n = 0; n < NSAMP; ++n) {
        bpos += fin[n*NSLOT + 76]; bneg += fin[n*NSLOT + 77];
        pos  += fin[n*NSLOT + 78]; neg  += fin[n*NSLOT + 79];
    }
    const float tt = pos + neg;
    const float bce_mean = ((neg / tt) * bpos + (pos / tt) * bneg) / (float)NPIX;

    out[0] = seg_loss;
    out[1] = 20.f * bce_mean;
    out[2] = att_loss;
}

extern "C" void kernel_launch(void* const* d_in, const int* in_sizes, int n_in,
                              void* d_out, int out_size, void* d_ws, size_t ws_size,
                              hipStream_t stream) {
    const float* segin    = (const float*)d_in[0];
    const float* edgein   = (const float*)d_in[1];
    const int*   segmask  = (const int*)d_in[2];
    const int*   edgemask = (const int*)d_in[3];
    float* ws  = (float*)d_ws;
    float* fin = ws + FINAL_OFF;
    float* out = (float*)d_out;

    joint_loss_main<<<NBLK, 256, 0, stream>>>(segin, edgein, segmask, edgemask, ws);
    reduce_partials<<<NSAMP * NSLOT, 64, 0, stream>>>(ws, fin);
    finalize<<<1, 64, 0, stream>>>(fin, out);
}